// Round 5
// baseline (746.987 us; speedup 1.0000x reference)
//
#include <hip/hip_runtime.h>
#include <math.h>

#define HID 128
#define NUM_G 20
#define EF 4
#define NN 20000
#define NE 640000
#define K1 288            // 280 padded to 9*32
#define KN1 256           // node GEMM1 K
#define TS 136            // LDS stride (bf16): 272B rows -> 2-way conflict only (free)
#define RBFS 40

typedef __attribute__((ext_vector_type(8))) short short8;
typedef __attribute__((ext_vector_type(4))) short short4v;
typedef __attribute__((ext_vector_type(4))) float floatx4;

__device__ __forceinline__ float silu_f(float v){ return v / (1.0f + __expf(-v)); }
__device__ __forceinline__ float sigm_f(float v){ return 1.0f / (1.0f + __expf(-v)); }
__device__ __forceinline__ unsigned short f2bf(float v){
    unsigned int u = __float_as_uint(v);
    u = (u + 0x7fffu + ((u >> 16) & 1u)) >> 16;
    return (unsigned short)u;
}
__device__ __forceinline__ float bf2f(unsigned int u){
    return __uint_as_float(u << 16);
}

__global__ __launch_bounds__(256) void prep_h_kernel(
    const float* __restrict__ h, unsigned short* __restrict__ h_bf)
{
    int i = (blockIdx.x * 256 + threadIdx.x) * 4;
    float4 v = *(const float4*)(h + i);
    short4v o;
    o[0] = (short)f2bf(v.x); o[1] = (short)f2bf(v.y);
    o[2] = (short)f2bf(v.z); o[3] = (short)f2bf(v.w);
    *(short4v*)(h_bf + i) = o;
}

__global__ __launch_bounds__(320) void prep_w_kernel(
    const float* __restrict__ W_e1, const float* __restrict__ W_e2,
    const float* __restrict__ W_x1, const float* __restrict__ W_n1,
    const float* __restrict__ W_n2,
    unsigned short* __restrict__ WT_e1, unsigned short* __restrict__ WT_e2,
    unsigned short* __restrict__ WT_x1, unsigned short* __restrict__ WT_n1,
    unsigned short* __restrict__ WT_n2)
{
    int n = blockIdx.x;
    int t = threadIdx.x;
    if (t < K1)  WT_e1[n*K1  + t] = (t < 280) ? f2bf(W_e1[t*HID + n]) : (unsigned short)0;
    if (t < KN1) WT_n1[n*KN1 + t] = f2bf(W_n1[t*HID + n]);
    if (t < HID) {
        WT_e2[n*HID + t] = f2bf(W_e2[t*HID + n]);
        WT_x1[n*HID + t] = f2bf(W_x1[t*HID + n]);
        WT_n2[n*HID + t] = f2bf(W_n2[t*HID + n]);
    }
}

// ---- counting sort of edges by dst ----
__global__ __launch_bounds__(256) void hist_kernel(
    const int* __restrict__ edge_index, int* __restrict__ counts)
{
    int e = blockIdx.x * 256 + threadIdx.x;
    atomicAdd(&counts[edge_index[NE + e]], 1);
}

__global__ __launch_bounds__(256) void scan_kernel(
    const int* __restrict__ counts, int* __restrict__ cursor)
{
    __shared__ int part[256];
    const int t = threadIdx.x;
    const int CH = (NN + 255) / 256;
    int base = t * CH;
    int s = 0;
    for (int i = 0; i < CH; ++i) { int idx = base + i; if (idx < NN) s += counts[idx]; }
    part[t] = s; __syncthreads();
    for (int off = 1; off < 256; off <<= 1) {
        int v = (t >= off) ? part[t - off] : 0;
        __syncthreads();
        part[t] += v;
        __syncthreads();
    }
    int run = (t == 0) ? 0 : part[t - 1];
    for (int i = 0; i < CH; ++i) {
        int idx = base + i;
        if (idx < NN) { cursor[idx] = run; run += counts[idx]; }
    }
}

__global__ __launch_bounds__(256) void scatter_kernel(
    const int* __restrict__ edge_index, int* __restrict__ cursor,
    int* __restrict__ order)
{
    int e = blockIdx.x * 256 + threadIdx.x;
    int d = edge_index[NE + e];
    int pos = atomicAdd(&cursor[d], 1);
    order[pos] = e;
}

// ---- edge kernel: ONE WAVE per block, 32 sorted edges (2 row-tiles share each B frag) ----
__global__ __launch_bounds__(64, 4) void egnn_edge_mfma(
    const float* __restrict__ x, const float* __restrict__ edge_attr,
    const int* __restrict__ edge_index, const int* __restrict__ order,
    const unsigned short* __restrict__ h_bf,
    const unsigned short* __restrict__ WT_e1,
    const unsigned short* __restrict__ WT_e2,
    const unsigned short* __restrict__ WT_x1,
    const float* __restrict__ b_e1, const float* __restrict__ b_e2,
    const float* __restrict__ W_g,  const float* __restrict__ b_g,
    const float* __restrict__ b_x1, const float* __restrict__ W_x2,
    float* __restrict__ agg, float* __restrict__ dxv)
{
    __shared__ __align__(16) unsigned short T[32*TS];      // m1, then m2
    __shared__ __align__(16) unsigned short RBF[32*RBFS];
    __shared__ int   s_eid[32];
    __shared__ int   s_dst[33];    // [32] = -1 sentinel
    __shared__ int   s_src[32];
    __shared__ float s_rel[96];
    __shared__ float s_r[32];
    __shared__ float s_g[32];
    __shared__ float s_vec[96];

    const int lane = threadIdx.x;
    const int quad = lane >> 4;
    const int l15  = lane & 15;
    const int e0   = blockIdx.x * 32;

    if (lane < 32) {
        int e = order[e0 + lane];
        s_eid[lane] = e;
        int s = edge_index[e];
        int d = edge_index[NE + e];
        s_src[lane] = s; s_dst[lane] = d;
        float rx = x[d*3+0] - x[s*3+0];
        float ry = x[d*3+1] - x[s*3+1];
        float rz = x[d*3+2] - x[s*3+2];
        float r  = sqrtf(rx*rx + ry*ry + rz*rz + 1e-8f);
        s_rel[lane*3+0] = rx; s_rel[lane*3+1] = ry; s_rel[lane*3+2] = rz;
        s_r[lane] = r;
    }
    if (lane == 32) s_dst[32] = -1;
    __builtin_amdgcn_wave_barrier();

    // RBF fill for 32 rows
    {
        const float step  = 10.0f / 19.0f;
        const float coeff = -0.5f / (step*step);
        #pragma unroll
        for (int u = 0; u < 2; ++u) {
            int row = u*16 + l15;
            float rr = s_r[row];
            int eid = s_eid[row];
            #pragma unroll
            for (int j = 0; j < 10; ++j) {
                int col = quad + j*4;
                unsigned short v;
                if (col < NUM_G) {
                    float d = rr - step*(float)col;
                    v = f2bf(__expf(coeff*d*d));
                } else if (col < NUM_G+EF) {
                    v = f2bf(edge_attr[(size_t)eid*EF + (col-NUM_G)]);
                } else v = 0;
                RBF[row*RBFS + col] = v;
            }
        }
    }
    __builtin_amdgcn_wave_barrier();

    const int nd0 = s_dst[l15],    ns0 = s_src[l15];
    const int nd1 = s_dst[16+l15], ns1 = s_src[16+l15];
    const unsigned short* hd0 = h_bf + (size_t)nd0*HID + quad*8;
    const unsigned short* hs0 = h_bf + (size_t)ns0*HID + quad*8;
    const unsigned short* hd1 = h_bf + (size_t)nd1*HID + quad*8;
    const unsigned short* hs1 = h_bf + (size_t)ns1*HID + quad*8;

    floatx4 acc0[8], acc1[8];
    #pragma unroll
    for (int t = 0; t < 8; ++t) { acc0[t] = (floatx4){0,0,0,0}; acc1[t] = (floatx4){0,0,0,0}; }

    // GEMM1: K=288, B loaded once per (kc,t), used for both row tiles
    #pragma unroll
    for (int kc = 0; kc < 9; ++kc) {
        short8 a0, a1;
        if (kc < 4)      { a0 = *(const short8*)(hd0 + kc*32);     a1 = *(const short8*)(hd1 + kc*32); }
        else if (kc < 8) { a0 = *(const short8*)(hs0 + (kc-4)*32); a1 = *(const short8*)(hs1 + (kc-4)*32); }
        else             { a0 = *(const short8*)(&RBF[l15*RBFS + quad*8]);
                           a1 = *(const short8*)(&RBF[(16+l15)*RBFS + quad*8]); }
        #pragma unroll
        for (int t = 0; t < 8; ++t) {
            short8 b = *(const short8*)(WT_e1 + (size_t)(t*16+l15)*K1 + kc*32 + quad*8);
            acc0[t] = __builtin_amdgcn_mfma_f32_16x16x32_bf16(a0, b, acc0[t], 0, 0, 0);
            acc1[t] = __builtin_amdgcn_mfma_f32_16x16x32_bf16(a1, b, acc1[t], 0, 0, 0);
        }
    }
    // epilogue 1: m1 -> T
    #pragma unroll
    for (int t = 0; t < 8; ++t) {
        int col = t*16 + l15;
        float bv = b_e1[col];
        #pragma unroll
        for (int i = 0; i < 4; ++i) {
            T[(quad*4+i)*TS + col]      = f2bf(silu_f(acc0[t][i] + bv));
            T[(16+quad*4+i)*TS + col]   = f2bf(silu_f(acc1[t][i] + bv));
        }
    }
    __builtin_amdgcn_wave_barrier();

    // GEMM2: m2 = silu(m1 @ W_e2 + b), gate
    #pragma unroll
    for (int t = 0; t < 8; ++t) { acc0[t] = (floatx4){0,0,0,0}; acc1[t] = (floatx4){0,0,0,0}; }
    #pragma unroll
    for (int kc = 0; kc < 4; ++kc) {
        short8 a0 = *(const short8*)(&T[l15*TS + kc*32 + quad*8]);
        short8 a1 = *(const short8*)(&T[(16+l15)*TS + kc*32 + quad*8]);
        #pragma unroll
        for (int t = 0; t < 8; ++t) {
            short8 b = *(const short8*)(WT_e2 + (size_t)(t*16+l15)*HID + kc*32 + quad*8);
            acc0[t] = __builtin_amdgcn_mfma_f32_16x16x32_bf16(a0, b, acc0[t], 0, 0, 0);
            acc1[t] = __builtin_amdgcn_mfma_f32_16x16x32_bf16(a1, b, acc1[t], 0, 0, 0);
        }
    }
    {
        float gp0[4] = {0,0,0,0}, gp1[4] = {0,0,0,0};
        #pragma unroll
        for (int t = 0; t < 8; ++t) {
            int col = t*16 + l15;
            float bv = b_e2[col];
            float wgv = W_g[col];
            #pragma unroll
            for (int i = 0; i < 4; ++i) {
                float m20 = silu_f(acc0[t][i] + bv);
                float m21 = silu_f(acc1[t][i] + bv);
                gp0[i] += m20 * wgv;
                gp1[i] += m21 * wgv;
                T[(quad*4+i)*TS + col]    = f2bf(m20);
                T[(16+quad*4+i)*TS + col] = f2bf(m21);
            }
        }
        const float bg0 = b_g[0];
        #pragma unroll
        for (int i = 0; i < 4; ++i) {
            gp0[i] += __shfl_xor(gp0[i], 1); gp0[i] += __shfl_xor(gp0[i], 2);
            gp0[i] += __shfl_xor(gp0[i], 4); gp0[i] += __shfl_xor(gp0[i], 8);
            gp1[i] += __shfl_xor(gp1[i], 1); gp1[i] += __shfl_xor(gp1[i], 2);
            gp1[i] += __shfl_xor(gp1[i], 4); gp1[i] += __shfl_xor(gp1[i], 8);
        }
        if (l15 == 0) {
            #pragma unroll
            for (int i = 0; i < 4; ++i) {
                s_g[quad*4 + i]    = sigm_f(gp0[i] + bg0);
                s_g[16+quad*4 + i] = sigm_f(gp1[i] + bg0);
            }
        }
    }
    __builtin_amdgcn_wave_barrier();

    // segmented msg reduce: lane owns cols 2*lane, 2*lane+1 over 32 rows
    {
        float am0 = 0.f, am1 = 0.f;
        #pragma unroll
        for (int r = 0; r < 32; ++r) {
            unsigned int pv = *(const unsigned int*)(&T[r*TS + lane*2]);
            float gr = s_g[r];
            am0 += bf2f(pv & 0xffffu) * gr;
            am1 += bf2f(pv >> 16) * gr;
            int dr = s_dst[r];
            if (dr != s_dst[r+1]) {
                atomicAdd(&agg[(size_t)dr*HID + lane*2],     am0);
                atomicAdd(&agg[(size_t)dr*HID + lane*2 + 1], am1);
                am0 = 0.f; am1 = 0.f;
            }
        }
    }

    // GEMM3: coord head
    #pragma unroll
    for (int t = 0; t < 8; ++t) { acc0[t] = (floatx4){0,0,0,0}; acc1[t] = (floatx4){0,0,0,0}; }
    #pragma unroll
    for (int kc = 0; kc < 4; ++kc) {
        short8 a0 = *(const short8*)(&T[l15*TS + kc*32 + quad*8]);
        short8 a1 = *(const short8*)(&T[(16+l15)*TS + kc*32 + quad*8]);
        #pragma unroll
        for (int t = 0; t < 8; ++t) {
            short8 b = *(const short8*)(WT_x1 + (size_t)(t*16+l15)*HID + kc*32 + quad*8);
            acc0[t] = __builtin_amdgcn_mfma_f32_16x16x32_bf16(a0, b, acc0[t], 0, 0, 0);
            acc1[t] = __builtin_amdgcn_mfma_f32_16x16x32_bf16(a1, b, acc1[t], 0, 0, 0);
        }
    }
    {
        float cp0[4] = {0,0,0,0}, cp1[4] = {0,0,0,0};
        #pragma unroll
        for (int t = 0; t < 8; ++t) {
            int col = t*16 + l15;
            float bv = b_x1[col];
            float wx = W_x2[col];
            #pragma unroll
            for (int i = 0; i < 4; ++i) {
                cp0[i] += silu_f(acc0[t][i] + bv) * wx;
                cp1[i] += silu_f(acc1[t][i] + bv) * wx;
            }
        }
        #pragma unroll
        for (int i = 0; i < 4; ++i) {
            cp0[i] += __shfl_xor(cp0[i], 1); cp0[i] += __shfl_xor(cp0[i], 2);
            cp0[i] += __shfl_xor(cp0[i], 4); cp0[i] += __shfl_xor(cp0[i], 8);
            cp1[i] += __shfl_xor(cp1[i], 1); cp1[i] += __shfl_xor(cp1[i], 2);
            cp1[i] += __shfl_xor(cp1[i], 4); cp1[i] += __shfl_xor(cp1[i], 8);
        }
        if (l15 < 3) {
            #pragma unroll
            for (int i = 0; i < 4; ++i) {
                int r0 = quad*4 + i;
                int r1 = 16 + quad*4 + i;
                s_vec[r0*3 + l15] = s_rel[r0*3 + l15] / (s_r[r0] + 1.0f) * tanhf(cp0[i]);
                s_vec[r1*3 + l15] = s_rel[r1*3 + l15] / (s_r[r1] + 1.0f) * tanhf(cp1[i]);
            }
        }
    }
    __builtin_amdgcn_wave_barrier();

    if (lane < 3) {
        float a = 0.f;
        #pragma unroll
        for (int r = 0; r < 32; ++r) {
            a += s_vec[r*3 + lane];
            int dr = s_dst[r];
            if (dr != s_dst[r+1]) {
                atomicAdd(&dxv[(size_t)dr*3 + lane], a);
                a = 0.f;
            }
        }
    }
}

// ---- node kernel: ONE WAVE per block, 16 nodes ----
__global__ __launch_bounds__(64, 4) void egnn_node_mfma(
    const float* __restrict__ h, const float* __restrict__ x,
    const int* __restrict__ mask,
    const unsigned short* __restrict__ h_bf,
    const float* __restrict__ agg, const float* __restrict__ dxv,
    const unsigned short* __restrict__ WT_n1, const float* __restrict__ b_n1,
    const unsigned short* __restrict__ WT_n2, const float* __restrict__ b_n2,
    float* __restrict__ h_out, float* __restrict__ x_out)
{
    __shared__ __align__(16) unsigned short T[16*TS];

    const int lane = threadIdx.x;
    const int quad = lane >> 4;
    const int l15  = lane & 15;
    const int n0   = blockIdx.x * 16;

    if (lane < 48) {
        int r = lane / 3, c = lane % 3;
        int n = n0 + r;
        x_out[n*3 + c] = x[n*3 + c] + dxv[n*3 + c] * (float)mask[n];
    }

    const int node = n0 + l15;
    short8 a1[8];
    #pragma unroll
    for (int kc = 0; kc < 4; ++kc) {
        const float* p = agg + (size_t)node*HID + kc*32 + quad*8;
        float4 f0 = *(const float4*)(p);
        float4 f1 = *(const float4*)(p + 4);
        short8 v;
        v[0]=(short)f2bf(f0.x); v[1]=(short)f2bf(f0.y); v[2]=(short)f2bf(f0.z); v[3]=(short)f2bf(f0.w);
        v[4]=(short)f2bf(f1.x); v[5]=(short)f2bf(f1.y); v[6]=(short)f2bf(f1.z); v[7]=(short)f2bf(f1.w);
        a1[kc] = v;
    }
    #pragma unroll
    for (int kc = 0; kc < 4; ++kc)
        a1[4+kc] = *(const short8*)(h_bf + (size_t)node*HID + kc*32 + quad*8);

    floatx4 acc[8];
    #pragma unroll
    for (int t = 0; t < 8; ++t) acc[t] = (floatx4){0,0,0,0};
    #pragma unroll
    for (int kc = 0; kc < 8; ++kc) {
        #pragma unroll
        for (int t = 0; t < 8; ++t) {
            short8 b = *(const short8*)(WT_n1 + (size_t)(t*16+l15)*KN1 + kc*32 + quad*8);
            acc[t] = __builtin_amdgcn_mfma_f32_16x16x32_bf16(a1[kc], b, acc[t], 0, 0, 0);
        }
    }
    #pragma unroll
    for (int t = 0; t < 8; ++t) {
        int col = t*16 + l15;
        float bv = b_n1[col];
        #pragma unroll
        for (int i = 0; i < 4; ++i)
            T[(quad*4+i)*TS + col] = f2bf(silu_f(acc[t][i] + bv));
    }
    __builtin_amdgcn_wave_barrier();

    short8 a2[4];
    #pragma unroll
    for (int kc = 0; kc < 4; ++kc)
        a2[kc] = *(const short8*)(&T[l15*TS + kc*32 + quad*8]);
    #pragma unroll
    for (int t = 0; t < 8; ++t) acc[t] = (floatx4){0,0,0,0};
    #pragma unroll
    for (int kc = 0; kc < 4; ++kc) {
        #pragma unroll
        for (int t = 0; t < 8; ++t) {
            short8 b = *(const short8*)(WT_n2 + (size_t)(t*16+l15)*HID + kc*32 + quad*8);
            acc[t] = __builtin_amdgcn_mfma_f32_16x16x32_bf16(a2[kc], b, acc[t], 0, 0, 0);
        }
    }
    #pragma unroll
    for (int t = 0; t < 8; ++t) {
        int col = t*16 + l15;
        float bv = b_n2[col];
        #pragma unroll
        for (int i = 0; i < 4; ++i) {
            int n = n0 + quad*4 + i;
            h_out[(size_t)n*HID + col] = h[(size_t)n*HID + col] + acc[t][i] + bv;
        }
    }
}

extern "C" void kernel_launch(void* const* d_in, const int* in_sizes, int n_in,
                              void* d_out, int out_size, void* d_ws, size_t ws_size,
                              hipStream_t stream) {
    const float* h          = (const float*)d_in[0];
    const float* x          = (const float*)d_in[1];
    const float* edge_attr  = (const float*)d_in[2];
    const int*   edge_index = (const int*)  d_in[3];
    const int*   mask       = (const int*)  d_in[4];
    const float* W_e1 = (const float*)d_in[5];
    const float* b_e1 = (const float*)d_in[6];
    const float* W_e2 = (const float*)d_in[7];
    const float* b_e2 = (const float*)d_in[8];
    const float* W_g  = (const float*)d_in[9];
    const float* b_g  = (const float*)d_in[10];
    const float* W_n1 = (const float*)d_in[11];
    const float* b_n1 = (const float*)d_in[12];
    const float* W_n2 = (const float*)d_in[13];
    const float* b_n2 = (const float*)d_in[14];
    const float* W_x1 = (const float*)d_in[15];
    const float* b_x1 = (const float*)d_in[16];
    const float* W_x2 = (const float*)d_in[17];

    char* ws = (char*)d_ws;
    float* agg = (float*)ws;                       ws += (size_t)NN*HID*4;
    float* dxv = (float*)ws;                       ws += (size_t)NN*3*4;
    int*   counts = (int*)ws;                      ws += (size_t)NN*4;
    int*   cursor = (int*)ws;                      ws += (size_t)NN*4;
    int*   order  = (int*)ws;                      ws += (size_t)NE*4;
    unsigned short* h_bf  = (unsigned short*)ws;   ws += (size_t)NN*HID*2;
    unsigned short* WT_e1 = (unsigned short*)ws;   ws += (size_t)HID*K1*2;
    unsigned short* WT_e2 = (unsigned short*)ws;   ws += (size_t)HID*HID*2;
    unsigned short* WT_x1 = (unsigned short*)ws;   ws += (size_t)HID*HID*2;
    unsigned short* WT_n1 = (unsigned short*)ws;   ws += (size_t)HID*KN1*2;
    unsigned short* WT_n2 = (unsigned short*)ws;   ws += (size_t)HID*HID*2;

    hipMemsetAsync(agg, 0, ((size_t)NN*HID + (size_t)NN*3)*sizeof(float), stream);
    hipMemsetAsync(counts, 0, (size_t)NN*sizeof(int), stream);

    prep_h_kernel<<<2500, 256, 0, stream>>>(h, h_bf);
    prep_w_kernel<<<128, 320, 0, stream>>>(W_e1, W_e2, W_x1, W_n1, W_n2,
                                           WT_e1, WT_e2, WT_x1, WT_n1, WT_n2);
    hist_kernel<<<NE/256, 256, 0, stream>>>(edge_index, counts);
    scan_kernel<<<1, 256, 0, stream>>>(counts, cursor);
    scatter_kernel<<<NE/256, 256, 0, stream>>>(edge_index, cursor, order);

    egnn_edge_mfma<<<NE/32, 64, 0, stream>>>(
        x, edge_attr, edge_index, order, h_bf, WT_e1, WT_e2, WT_x1,
        b_e1, b_e2, W_g, b_g, b_x1, W_x2, agg, dxv);

    float* h_out = (float*)d_out;
    float* x_out = h_out + (size_t)NN*HID;

    egnn_node_mfma<<<NN/16, 64, 0, stream>>>(
        h, x, mask, h_bf, agg, dxv, WT_n1, b_n1, WT_n2, b_n2, h_out, x_out);
}